// Round 1
// baseline (345.088 us; speedup 1.0000x reference)
//
#include <hip/hip_runtime.h>
#include <stdint.h>

#define TEMP      0.07f
#define BATCH     256
#define NROWS     32768
#define DIM       2048
#define KNEG      8192
#define HALF_CNT  (BATCH * NROWS / 2)

// RNG_MODE: 0 = partitionable threefry (JAX >= 0.4.36 default: foldlike split,
//               bits = out0 ^ out1 with (hi,lo) 64-bit iota counters)
//           2 = legacy threefry (split-half counter mode)
#define RNG_MODE 0

typedef __attribute__((ext_vector_type(8))) short bf16x8;
typedef __attribute__((ext_vector_type(4))) float f32x4;

// ---------------------------------------------------------------- threefry2x32
__host__ __device__ inline void tf2x32(uint32_t ka, uint32_t kb,
                                       uint32_t x0, uint32_t x1,
                                       uint32_t& o0, uint32_t& o1) {
  uint32_t ks2 = ka ^ kb ^ 0x1BD11BDAu;
#define TFR(r) { x0 += x1; x1 = (x1 << r) | (x1 >> (32 - r)); x1 ^= x0; }
  x0 += ka; x1 += kb;
  TFR(13) TFR(15) TFR(26) TFR(6)
  x0 += kb;  x1 += ks2 + 1u;
  TFR(17) TFR(29) TFR(16) TFR(24)
  x0 += ks2; x1 += ka + 2u;
  TFR(13) TFR(15) TFR(26) TFR(6)
  x0 += ka;  x1 += kb + 3u;
  TFR(17) TFR(29) TFR(16) TFR(24)
  x0 += kb;  x1 += ks2 + 4u;
  TFR(13) TFR(15) TFR(26) TFR(6)
  x0 += ks2; x1 += ka + 5u;
#undef TFR
  o0 = x0; o1 = x1;
}

// 23-bit uniform mantissa bits for flat position q of a (BATCH, NROWS) draw.
// Monotone in the gumbel value, so ordering/argmax/top-k on these == on gumbels.
__device__ inline uint32_t ubits_at(uint32_t ka, uint32_t kb, uint32_t q) {
#if RNG_MODE == 0
  uint32_t a, b; tf2x32(ka, kb, 0u, q, a, b);
  return (a ^ b) >> 9;
#else
  bool lo = q < HALF_CNT;
  uint32_t x0 = lo ? q : q - HALF_CNT;
  uint32_t x1 = lo ? q + HALF_CNT : q;
  uint32_t a, b; tf2x32(ka, kb, x0, x1, a, b);
  return (lo ? a : b) >> 9;
#endif
}

// ---------------------------------------------------------------- block reduce
__device__ inline float block_sum(float v, float* sm) {
  __syncthreads();
  const int lane = threadIdx.x & 63;
  const int w = threadIdx.x >> 6;
  const int nw = blockDim.x >> 6;
  for (int o = 32; o; o >>= 1) v += __shfl_down(v, o, 64);
  if (lane == 0) sm[w] = v;
  __syncthreads();
  if (w == 0) {
    float x = (lane < nw) ? sm[lane] : 0.f;
    for (int o = 8; o; o >>= 1) x += __shfl_down(x, o, 64);
    if (lane == 0) sm[0] = x;
  }
  __syncthreads();
  return sm[0];
}

// ---------------------------------------------------------------- GEMM: mat_sim
#define BM 128
#define BN 128
#define BKK 64

__device__ inline uint32_t pk2(float a, float b) {  // 2x fp32 -> packed bf16 (RNE)
  uint32_t ua = __float_as_uint(a), ub = __float_as_uint(b);
  ua = (ua + 0x7FFFu + ((ua >> 16) & 1u)) >> 16;
  ub = (ub + 0x7FFFu + ((ub >> 16) & 1u)) >> 16;
  return ua | (ub << 16);
}

__global__ __launch_bounds__(256) void gemm_matsim(
    const float* __restrict__ A,   // f_nv [BATCH][DIM]
    const float* __restrict__ B,   // features [NROWS][DIM]
    float* __restrict__ C) {       // mat_sim [BATCH][NROWS]
  __shared__ short As[BM * BKK];
  __shared__ short Bs[BN * BKK];
  const int t = threadIdx.x;
  const int bm = blockIdx.x & 1;
  const int bn = blockIdx.x >> 1;
  const int row_a0 = bm * BM, row_b0 = bn * BN;
  const int lane = t & 63, wave = t >> 6;
  const int wr = wave >> 1, wc = wave & 1;
  const int srow = t >> 4, sc4 = t & 15;

  f32x4 acc[4][4] = {};

  for (int k0 = 0; k0 < DIM; k0 += BKK) {
    __syncthreads();
#pragma unroll
    for (int s = 0; s < 8; ++s) {
      int r = srow + 16 * s;
      const float4 va = *(const float4*)&A[(size_t)(row_a0 + r) * DIM + k0 + sc4 * 4];
      const float4 vb = *(const float4*)&B[(size_t)(row_b0 + r) * DIM + k0 + sc4 * 4];
      uint32_t off = (uint32_t)r * (BKK * 2) + (((uint32_t)sc4 * 8) ^ (((uint32_t)r & 7u) << 4));
      *(uint2*)((char*)As + off) = make_uint2(pk2(va.x, va.y), pk2(va.z, va.w));
      *(uint2*)((char*)Bs + off) = make_uint2(pk2(vb.x, vb.y), pk2(vb.z, vb.w));
    }
    __syncthreads();
#pragma unroll
    for (int kk = 0; kk < 2; ++kk) {
      bf16x8 af[4], bfr[4];
      const uint32_t kb = (uint32_t)(kk * 64 + ((lane >> 4) << 4));
#pragma unroll
      for (int m = 0; m < 4; ++m) {
        uint32_t rr = (uint32_t)(wr * 64 + m * 16 + (lane & 15));
        af[m] = *(const bf16x8*)((const char*)As + rr * (BKK * 2) + (kb ^ ((rr & 7u) << 4)));
      }
#pragma unroll
      for (int n = 0; n < 4; ++n) {
        uint32_t rr = (uint32_t)(wc * 64 + n * 16 + (lane & 15));
        bfr[n] = *(const bf16x8*)((const char*)Bs + rr * (BKK * 2) + (kb ^ ((rr & 7u) << 4)));
      }
#pragma unroll
      for (int m = 0; m < 4; ++m)
#pragma unroll
        for (int n = 0; n < 4; ++n)
          acc[m][n] = __builtin_amdgcn_mfma_f32_16x16x32_bf16(af[m], bfr[n], acc[m][n], 0, 0, 0);
    }
  }
  const int col_l = lane & 15, rg = (lane >> 4) * 4;
#pragma unroll
  for (int m = 0; m < 4; ++m)
#pragma unroll
    for (int n = 0; n < 4; ++n) {
      size_t base = (size_t)(row_a0 + wr * 64 + m * 16 + rg) * NROWS
                  + (size_t)(row_b0 + wc * 64 + n * 16 + col_l);
#pragma unroll
      for (int r = 0; r < 4; ++r)
        C[base + (size_t)r * NROWS] = acc[m][n][r];
    }
}

// -------------------------------------------------- per-row sampling + CE loss
__global__ __launch_bounds__(1024) void sample_loss(
    const float* __restrict__ f, const float* __restrict__ f_nv,
    const float* __restrict__ features, const int* __restrict__ labels,
    const int* __restrict__ indexes, const float* __restrict__ mat_sim,
    float* __restrict__ row_loss,
    uint32_t k1a, uint32_t k1b, uint32_t k2a, uint32_t k2b,
    uint32_t k3a, uint32_t k3b) {
  __shared__ uint32_t keys[NROWS];      // 128 KiB: 23-bit sortable uniform bits
  __shared__ uint32_t hist[256];
  __shared__ unsigned long long am1, am2;
  __shared__ int tie_j[128];
  __shared__ int tie_cnt;
  __shared__ float sred[16];
  __shared__ float swm[16], sws[16];
  __shared__ uint32_t bc_prefix, bc_rem;
  __shared__ int blab_s;

  const int t = threadIdx.x;
  const int i = blockIdx.x;
  const size_t mbase = (size_t)i * NROWS;

  if (t == 0) {
    blab_s = labels[indexes[i]];
    am1 = 0ull; am2 = 0ull; tie_cnt = 0;
  }
  __syncthreads();
  const int blab = blab_s;

  // phase 1: keys for g3 (masked -> 0), argmax of g1/g2 over positives
#pragma unroll 2
  for (int s = 0; s < NROWS / 1024; ++s) {
    int j = t + 1024 * s;
    uint32_t q = (uint32_t)i * NROWS + (uint32_t)j;
    int lab = labels[j];
    if (lab == blab) {
      keys[j] = 0u;
      unsigned long long lo = (unsigned long long)(uint32_t)(NROWS - 1 - j);
      uint32_t u1 = ubits_at(k1a, k1b, q);
      uint32_t u2 = ubits_at(k2a, k2b, q);
      atomicMax(&am1, ((unsigned long long)u1 << 32) | lo);
      atomicMax(&am2, ((unsigned long long)u2 << 32) | lo);
    } else {
      keys[j] = ubits_at(k3a, k3b, q);
    }
  }
  __syncthreads();

  const int jw = NROWS - 1 - (int)(unsigned)(am1 & 0xFFFFFFFFull);  // g1 -> wogan (mat)
  const int jp = NROWS - 1 - (int)(unsigned)(am2 & 0xFFFFFFFFull);  // g2 -> inter (mat_sim)

  // exact fp32 positive logits
  const int bank = indexes[i];
  float d1 = 0.f, d2 = 0.f, d3 = 0.f;
  for (int d = t; d < DIM; d += 1024) {
    float fnv = f_nv[(size_t)i * DIM + d];
    d1 += fnv * features[(size_t)bank * DIM + d];
    d2 += f[(size_t)i * DIM + d] * features[(size_t)jw * DIM + d];
    d3 += fnv * features[(size_t)jp * DIM + d];
  }
  const float l_pos = block_sum(d1, sred);
  const float posw  = block_sum(d2, sred);
  const float posv  = block_sum(d3, sred);

  // 3-pass radix select: K-th largest of the 23-bit keys
  uint32_t prefix = 0, remaining = KNEG;
  const int shifts[3] = {15, 7, 0};
  const int nbits[3]  = {8, 8, 7};
  for (int p = 0; p < 3; ++p) {
    const int sh = shifts[p];
    const int nb = 1 << nbits[p];
    if (t < nb) hist[t] = 0u;
    __syncthreads();
    for (int s = 0; s < NROWS / 1024; ++s) {
      int j = t + 1024 * s;
      uint32_t k = keys[j];
      bool ok = (p == 0) || ((k >> (sh + nbits[p])) == prefix);
      if (ok) atomicAdd(&hist[(k >> sh) & (uint32_t)(nb - 1)], 1u);
    }
    __syncthreads();
    if (t == 0) {
      uint32_t c = 0; int b = nb - 1;
      for (;; --b) {
        c += hist[b];
        if (c >= remaining || b == 0) break;
      }
      bc_prefix = (prefix << nbits[p]) | (uint32_t)b;
      bc_rem = remaining - (c - hist[b]);
    }
    __syncthreads();
    prefix = bc_prefix; remaining = bc_rem;
  }
  const uint32_t T = prefix;
  const uint32_t need = remaining;  // #ties at T to include (smallest j first)

  // gather negatives (coalesced full-row read) + online LSE
  float m = -INFINITY, ssum = 0.f;
  for (int s = 0; s < NROWS / 1024; ++s) {
    int j = t + 1024 * s;
    uint32_t k = keys[j];
    if (k > T) {
      float v = mat_sim[mbase + j] / TEMP;
      if (v <= m) ssum += expf(v - m);
      else { ssum = ssum * expf(m - v) + 1.0f; m = v; }
    } else if (k == T) {
      int p = atomicAdd(&tie_cnt, 1);
      if (p < 128) tie_j[p] = j;
    }
  }
  // reduce (m, ssum)
  for (int o = 32; o; o >>= 1) {
    float m2 = __shfl_down(m, o, 64);
    float s2 = __shfl_down(ssum, o, 64);
    if (m2 > m) { ssum = ssum * expf(m - m2) + s2; m = m2; }
    else if (m2 != -INFINITY) ssum += s2 * expf(m2 - m);
  }
  if ((t & 63) == 0) { swm[t >> 6] = m; sws[t >> 6] = ssum; }
  __syncthreads();
  if (t < 64) {
    float mm = (t < 16) ? swm[t] : -INFINITY;
    float ss = (t < 16) ? sws[t] : 0.f;
    for (int o = 8; o; o >>= 1) {
      float m2 = __shfl_down(mm, o, 64);
      float s2 = __shfl_down(ss, o, 64);
      if (m2 > mm) { ss = ss * expf(mm - m2) + s2; mm = m2; }
      else if (m2 != -INFINITY) ss += s2 * expf(m2 - mm);
    }
    if (t == 0) { swm[0] = mm; sws[0] = ss; }
  }
  __syncthreads();

  if (t == 0) {
    float M = swm[0], S = sws[0];
    int tc = tie_cnt;
    if (tc <= 128) {
      for (int a2 = 1; a2 < tc; ++a2) {            // sort ties by index asc
        int v = tie_j[a2]; int b2 = a2 - 1;
        while (b2 >= 0 && tie_j[b2] > v) { tie_j[b2 + 1] = tie_j[b2]; --b2; }
        tie_j[b2 + 1] = v;
      }
      for (uint32_t r = 0; r < need; ++r) {
        float v = mat_sim[mbase + tie_j[r]] / TEMP;
        if (v <= M) S += expf(v - M);
        else { S = S * expf(M - v) + 1.0f; M = v; }
      }
    } else {                                        // (practically unreachable)
      uint32_t taken = 0;
      for (int j = 0; j < NROWS && taken < need; ++j) {
        if (keys[j] == T) {
          float v = mat_sim[mbase + j] / TEMP;
          if (v <= M) S += expf(v - M);
          else { S = S * expf(M - v) + 1.0f; M = v; }
          ++taken;
        }
      }
    }
    float lp = l_pos / TEMP, pv = posv / TEMP, pw = posw / TEMP;
    float L = 0.f;
    { float X = fmaxf(M, lp); L += X + logf(expf(lp - X) + S * expf(M - X)) - lp; }
    { float X = fmaxf(M, pv); L += X + logf(expf(pv - X) + S * expf(M - X)) - pv; }
    { float X = fmaxf(M, pw); L += X + logf(expf(pw - X) + S * expf(M - X)) - pw; }
    row_loss[i] = L;
  }
}

// ---------------------------------------------------------------- finalize loss
__global__ void finalize_loss(const float* __restrict__ row_loss,
                              float* __restrict__ out) {
  __shared__ float sm[4];
  int t = threadIdx.x;
  float v = row_loss[t];
  for (int o = 32; o; o >>= 1) v += __shfl_down(v, o, 64);
  if ((t & 63) == 0) sm[t >> 6] = v;
  __syncthreads();
  if (t == 0) out[0] = (sm[0] + sm[1] + sm[2] + sm[3]) * (1.0f / BATCH);
}

// ----------------------------------------------------- copy features -> output
__global__ void copy_features(const float* __restrict__ src,
                              float* __restrict__ dst) {
  const int n = NROWS * DIM;
  const int stride = gridDim.x * blockDim.x;
  int idx = blockIdx.x * blockDim.x + threadIdx.x;
  for (; idx + 3 * stride < n; idx += 4 * stride) {
    float a0 = src[idx];
    float a1 = src[idx + stride];
    float a2 = src[idx + 2 * stride];
    float a3 = src[idx + 3 * stride];
    dst[idx] = a0; dst[idx + stride] = a1;
    dst[idx + 2 * stride] = a2; dst[idx + 3 * stride] = a3;
  }
  for (; idx < n; idx += stride) dst[idx] = src[idx];
}

// --------------------------------------------- momentum update of touched rows
__global__ __launch_bounds__(256) void update_rows(
    const float* __restrict__ f, const float* __restrict__ features,
    const int* __restrict__ indexes, float* __restrict__ outF) {
  __shared__ float sred[16];
  const int i = blockIdx.x;
  const int row = indexes[i];
  for (int i2 = i + 1; i2 < BATCH; ++i2)
    if (indexes[i2] == row) return;          // last occurrence wins
  const int t = threadIdx.x;
  float ss = 0.f;
  for (int d = t; d < DIM; d += 256) {
    float u = 0.2f * features[(size_t)row * DIM + d] + 0.8f * f[(size_t)i * DIM + d];
    ss += u * u;
  }
  ss = block_sum(ss, sred);
  float nrm = fmaxf(sqrtf(ss), 1e-12f);
  for (int d = t; d < DIM; d += 256) {
    float u = 0.2f * features[(size_t)row * DIM + d] + 0.8f * f[(size_t)i * DIM + d];
    outF[(size_t)row * DIM + d] = u / nrm;
  }
}

// ------------------------------------------------------------------- launcher
extern "C" void kernel_launch(void* const* d_in, const int* in_sizes, int n_in,
                              void* d_out, int out_size, void* d_ws, size_t ws_size,
                              hipStream_t stream) {
  (void)in_sizes; (void)n_in; (void)out_size; (void)d_ws; (void)ws_size;
  const float* f        = (const float*)d_in[0];
  const float* f_nv     = (const float*)d_in[1];
  const float* features = (const float*)d_in[2];
  const int*   labels   = (const int*)d_in[3];
  const int*   indexes  = (const int*)d_in[4];
  float* out = (float*)d_out;

  // scratch inside d_out (dead before copy_features overwrites it)
  float* mat_sim  = out + 4;
  float* row_loss = out + 4 + (size_t)BATCH * NROWS;

  // derive kg1..kg3 = split(key(42), 3) on host (exact threefry)
  uint32_t c[6];
#if RNG_MODE == 0
  { uint32_t a, b;
    tf2x32(0u, 42u, 0u, 0u, a, b); c[0] = a; c[1] = b;   // kg1
    tf2x32(0u, 42u, 0u, 1u, a, b); c[2] = a; c[3] = b;   // kg2
    tf2x32(0u, 42u, 0u, 2u, a, b); c[4] = a; c[5] = b; } // kg3
#else
  { uint32_t a, b;
    tf2x32(0u, 42u, 0u, 3u, a, b); c[0] = a; c[3] = b;
    tf2x32(0u, 42u, 1u, 4u, a, b); c[1] = a; c[4] = b;
    tf2x32(0u, 42u, 2u, 5u, a, b); c[2] = a; c[5] = b; } // kg1=(c0,c1) kg2=(c2,c3) kg3=(c4,c5)
#endif

  gemm_matsim<<<dim3(512), dim3(256), 0, stream>>>(f_nv, features, mat_sim);
  sample_loss<<<dim3(BATCH), dim3(1024), 0, stream>>>(
      f, f_nv, features, labels, indexes, mat_sim, row_loss,
      c[0], c[1], c[2], c[3], c[4], c[5]);
  finalize_loss<<<dim3(1), dim3(256), 0, stream>>>(row_loss, out);
  copy_features<<<dim3(4096), dim3(256), 0, stream>>>(features, out + 1);
  update_rows<<<dim3(BATCH), dim3(256), 0, stream>>>(f, features, indexes, out + 1);
}

// Round 2
// 288.969 us; speedup vs baseline: 1.1942x; 1.1942x over previous
//
#include <hip/hip_runtime.h>
#include <stdint.h>

#define TEMP      0.07f
#define BATCH     256
#define NROWS     32768
#define DIM       2048
#define KNEG      8192

typedef __attribute__((ext_vector_type(8))) short bf16x8;
typedef __attribute__((ext_vector_type(4))) float f32x4;

// ---------------------------------------------------------------- threefry2x32
__host__ __device__ inline void tf2x32(uint32_t ka, uint32_t kb,
                                       uint32_t x0, uint32_t x1,
                                       uint32_t& o0, uint32_t& o1) {
  uint32_t ks2 = ka ^ kb ^ 0x1BD11BDAu;
#define TFR(r) { x0 += x1; x1 = (x1 << r) | (x1 >> (32 - r)); x1 ^= x0; }
  x0 += ka; x1 += kb;
  TFR(13) TFR(15) TFR(26) TFR(6)
  x0 += kb;  x1 += ks2 + 1u;
  TFR(17) TFR(29) TFR(16) TFR(24)
  x0 += ks2; x1 += ka + 2u;
  TFR(13) TFR(15) TFR(26) TFR(6)
  x0 += ka;  x1 += kb + 3u;
  TFR(17) TFR(29) TFR(16) TFR(24)
  x0 += kb;  x1 += ks2 + 4u;
  TFR(13) TFR(15) TFR(26) TFR(6)
  x0 += ks2; x1 += ka + 5u;
#undef TFR
  o0 = x0; o1 = x1;
}

// partitionable threefry (JAX >= 0.4.36): bits = out0 ^ out1, counter = (0, q)
__device__ inline uint32_t ubits_at(uint32_t ka, uint32_t kb, uint32_t q) {
  uint32_t a, b; tf2x32(ka, kb, 0u, q, a, b);
  return (a ^ b) >> 9;
}

// ---------------------------------------------------------------- block reduce
__device__ inline float block_sum(float v, float* sm) {
  __syncthreads();
  const int lane = threadIdx.x & 63;
  const int w = threadIdx.x >> 6;
  const int nw = blockDim.x >> 6;
  for (int o = 32; o; o >>= 1) v += __shfl_down(v, o, 64);
  if (lane == 0) sm[w] = v;
  __syncthreads();
  if (w == 0) {
    float x = (lane < nw) ? sm[lane] : 0.f;
    for (int o = 8; o; o >>= 1) x += __shfl_down(x, o, 64);
    if (lane == 0) sm[0] = x;
  }
  __syncthreads();
  return sm[0];
}

// ------------------------------------------- fused GEMM + features->out copy
// BM=256 (whole batch, features read once), BN=128, BK=64.
#define BM 256
#define BN 128
#define BK 64
#define NT (DIM / BK)   // 32 K-steps

__device__ inline uint32_t pk2(float a, float b) {  // 2x fp32 -> packed bf16 (RNE)
  uint32_t ua = __float_as_uint(a), ub = __float_as_uint(b);
  ua = (ua + 0x7FFFu + ((ua >> 16) & 1u)) >> 16;
  ub = (ub + 0x7FFFu + ((ub >> 16) & 1u)) >> 16;
  return ua | (ub << 16);
}

__global__ __launch_bounds__(512, 2) void gemm_fused(
    const float* __restrict__ A,    // f_nv [256][2048]
    const float* __restrict__ B,    // features [32768][2048]
    float* __restrict__ C,          // mat_sim [256][32768]
    float* __restrict__ outF,       // out+1 (new_features)
    int copy_skip_rows) {           // copy only feature rows >= this
  __shared__ short As[2][BM * BK];  // 2 x 32 KiB bf16
  __shared__ short Bs[2][BN * BK];  // 2 x 16 KiB bf16
  const int t = threadIdx.x;
  const int bn = blockIdx.x;        // 256 blocks: 128 feature rows each
  const int lane = t & 63, wave = t >> 6;
  const int wr = wave >> 2, wc = wave & 3;   // 2 x 4 wave grid
  const int ld_row = t >> 4;        // 0..31
  const int ld_c4 = t & 15;         // float4 column

  float4 ra[8], rb[4];
  f32x4 acc[8][2] = {};

#define LOADT(k0)                                                              \
  {                                                                            \
    _Pragma("unroll")                                                          \
    for (int s = 0; s < 8; ++s)                                                \
      ra[s] = *(const float4*)&A[(size_t)(ld_row + 32 * s) * DIM + (k0) + ld_c4 * 4]; \
    _Pragma("unroll")                                                          \
    for (int s = 0; s < 4; ++s)                                                \
      rb[s] = *(const float4*)&B[(size_t)(bn * BN + ld_row + 32 * s) * DIM + (k0) + ld_c4 * 4]; \
  }

#define WRITET(buf, k0)                                                        \
  {                                                                            \
    _Pragma("unroll")                                                          \
    for (int s = 0; s < 8; ++s) {                                              \
      int r = ld_row + 32 * s;                                                 \
      uint32_t off = (uint32_t)r * (BK * 2) +                                  \
                     (((uint32_t)ld_c4 * 8) ^ (((uint32_t)r & 7u) << 4));      \
      *(uint2*)((char*)As[buf] + off) =                                        \
          make_uint2(pk2(ra[s].x, ra[s].y), pk2(ra[s].z, ra[s].w));            \
    }                                                                          \
    _Pragma("unroll")                                                          \
    for (int s = 0; s < 4; ++s) {                                              \
      int r = ld_row + 32 * s;                                                 \
      uint32_t off = (uint32_t)r * (BK * 2) +                                  \
                     (((uint32_t)ld_c4 * 8) ^ (((uint32_t)r & 7u) << 4));      \
      *(uint2*)((char*)Bs[buf] + off) =                                        \
          make_uint2(pk2(rb[s].x, rb[s].y), pk2(rb[s].z, rb[s].w));            \
      int g = bn * BN + r;                                                     \
      if (g >= copy_skip_rows) {                                               \
        float* d = &outF[(size_t)g * DIM + (k0) + ld_c4 * 4];                  \
        d[0] = rb[s].x; d[1] = rb[s].y; d[2] = rb[s].z; d[3] = rb[s].w;        \
      }                                                                        \
    }                                                                          \
  }

#define COMPUTET(buf)                                                          \
  {                                                                            \
    _Pragma("unroll")                                                          \
    for (int kk = 0; kk < 2; ++kk) {                                           \
      bf16x8 af[8], bfr[2];                                                    \
      const uint32_t kb = (uint32_t)(kk * 64 + ((lane >> 4) << 4));            \
      _Pragma("unroll")                                                        \
      for (int m = 0; m < 8; ++m) {                                            \
        uint32_t rr = (uint32_t)(wr * 128 + m * 16 + (lane & 15));             \
        af[m] = *(const bf16x8*)((const char*)As[buf] + rr * (BK * 2) +        \
                                 (kb ^ ((rr & 7u) << 4)));                     \
      }                                                                        \
      _Pragma("unroll")                                                        \
      for (int n = 0; n < 2; ++n) {                                            \
        uint32_t rr = (uint32_t)(wc * 32 + n * 16 + (lane & 15));              \
        bfr[n] = *(const bf16x8*)((const char*)Bs[buf] + rr * (BK * 2) +       \
                                  (kb ^ ((rr & 7u) << 4)));                    \
      }                                                                        \
      _Pragma("unroll")                                                        \
      for (int m = 0; m < 8; ++m)                                              \
        _Pragma("unroll")                                                      \
        for (int n = 0; n < 2; ++n)                                            \
          acc[m][n] = __builtin_amdgcn_mfma_f32_16x16x32_bf16(                 \
              af[m], bfr[n], acc[m][n], 0, 0, 0);                              \
    }                                                                          \
  }

  LOADT(0);
  WRITET(0, 0);
  __syncthreads();
  for (int t0 = 0; t0 < NT; ++t0) {
    if (t0 + 1 < NT) LOADT((t0 + 1) * BK);       // next tile in flight
    COMPUTET(t0 & 1);
    if (t0 + 1 < NT) {
      WRITET((t0 + 1) & 1, (t0 + 1) * BK);       // different buffer: no race
      __syncthreads();
    }
  }

  const int col_l = lane & 15, rg = (lane >> 4) * 4;
#pragma unroll
  for (int m = 0; m < 8; ++m)
#pragma unroll
    for (int n = 0; n < 2; ++n) {
      size_t base = (size_t)(wr * 128 + m * 16 + rg) * NROWS
                  + (size_t)(bn * BN + wc * 32 + n * 16 + col_l);
#pragma unroll
      for (int r = 0; r < 4; ++r)
        C[base + (size_t)r * NROWS] = acc[m][n][r];
    }
#undef LOADT
#undef WRITET
#undef COMPUTET
}

// -------------------------------------------------- per-row sampling + CE loss
__global__ __launch_bounds__(1024) void sample_loss(
    const float* __restrict__ f, const float* __restrict__ f_nv,
    const float* __restrict__ features, const int* __restrict__ labels,
    const int* __restrict__ indexes, const float* __restrict__ mat_sim,
    float* __restrict__ row_loss,
    uint32_t k1a, uint32_t k1b, uint32_t k2a, uint32_t k2b,
    uint32_t k3a, uint32_t k3b) {
  __shared__ uint32_t keys[NROWS];      // 128 KiB sortable uniform bits
  __shared__ uint32_t hist4[4][256];    // privatized histograms
  __shared__ uint32_t hist[256];
  __shared__ unsigned long long am1, am2;
  __shared__ int tie_j[128];
  __shared__ int tie_cnt;
  __shared__ float sred[16];
  __shared__ float swm[16], sws[16];
  __shared__ uint32_t bc_prefix, bc_rem;
  __shared__ int blab_s;

  const int t = threadIdx.x;
  const int i = blockIdx.x;
  const size_t mbase = (size_t)i * NROWS;

  if (t == 0) {
    blab_s = labels[indexes[i]];
    am1 = 0ull; am2 = 0ull; tie_cnt = 0;
  }
  __syncthreads();
  const int blab = blab_s;

  // phase 1: keys for g3 (positives -> 0), argmax of g1/g2 over positives
#pragma unroll 2
  for (int s = 0; s < NROWS / 1024; ++s) {
    int j = t + 1024 * s;
    uint32_t q = (uint32_t)i * NROWS + (uint32_t)j;
    int lab = labels[j];
    if (lab == blab) {
      keys[j] = 0u;
      unsigned long long lo = (unsigned long long)(uint32_t)(NROWS - 1 - j);
      uint32_t u1 = ubits_at(k1a, k1b, q);
      uint32_t u2 = ubits_at(k2a, k2b, q);
      atomicMax(&am1, ((unsigned long long)u1 << 32) | lo);
      atomicMax(&am2, ((unsigned long long)u2 << 32) | lo);
    } else {
      keys[j] = ubits_at(k3a, k3b, q);
    }
  }
  __syncthreads();

  const int jw = NROWS - 1 - (int)(unsigned)(am1 & 0xFFFFFFFFull);
  const int jp = NROWS - 1 - (int)(unsigned)(am2 & 0xFFFFFFFFull);

  // exact fp32 positive logits
  const int bank = indexes[i];
  float d1 = 0.f, d2 = 0.f, d3 = 0.f;
  for (int d = t; d < DIM; d += 1024) {
    float fnv = f_nv[(size_t)i * DIM + d];
    d1 += fnv * features[(size_t)bank * DIM + d];
    d2 += f[(size_t)i * DIM + d] * features[(size_t)jw * DIM + d];
    d3 += fnv * features[(size_t)jp * DIM + d];
  }
  const float l_pos = block_sum(d1, sred);
  const float posw  = block_sum(d2, sred);
  const float posv  = block_sum(d3, sred);

  // 3-pass radix select: K-th largest of the 23-bit keys
  uint32_t prefix = 0, remaining = KNEG;
  const int shifts[3] = {15, 7, 0};
  const int nbits[3]  = {8, 8, 7};
  for (int p = 0; p < 3; ++p) {
    const int sh = shifts[p];
    const int nb = 1 << nbits[p];
    ((uint32_t*)hist4)[t] = 0u;           // 1024 entries, blockDim 1024
    __syncthreads();
    const int hsel = t >> 8;              // 4-way privatization
    for (int s = 0; s < NROWS / 1024; ++s) {
      int j = t + 1024 * s;
      uint32_t k = keys[j];
      bool ok = (p == 0) || ((k >> (sh + nbits[p])) == prefix);
      if (ok) atomicAdd(&hist4[hsel][(k >> sh) & (uint32_t)(nb - 1)], 1u);
    }
    __syncthreads();
    if (t < nb) hist[t] = hist4[0][t] + hist4[1][t] + hist4[2][t] + hist4[3][t];
    __syncthreads();
    if (t == 0) {
      uint32_t c = 0; int b = nb - 1;
      for (;; --b) {
        c += hist[b];
        if (c >= remaining || b == 0) break;
      }
      bc_prefix = (prefix << nbits[p]) | (uint32_t)b;
      bc_rem = remaining - (c - hist[b]);
    }
    __syncthreads();
    prefix = bc_prefix; remaining = bc_rem;
  }
  const uint32_t T = prefix;
  const uint32_t need = remaining;

  // gather negatives (coalesced full-row read) + online LSE
  float m = -INFINITY, ssum = 0.f;
  for (int s = 0; s < NROWS / 1024; ++s) {
    int j = t + 1024 * s;
    uint32_t k = keys[j];
    if (k > T) {
      float v = mat_sim[mbase + j] / TEMP;
      if (v <= m) ssum += expf(v - m);
      else { ssum = ssum * expf(m - v) + 1.0f; m = v; }
    } else if (k == T) {
      int p = atomicAdd(&tie_cnt, 1);
      if (p < 128) tie_j[p] = j;
    }
  }
  for (int o = 32; o; o >>= 1) {
    float m2 = __shfl_down(m, o, 64);
    float s2 = __shfl_down(ssum, o, 64);
    if (m2 > m) { ssum = ssum * expf(m - m2) + s2; m = m2; }
    else if (m2 != -INFINITY) ssum += s2 * expf(m2 - m);
  }
  if ((t & 63) == 0) { swm[t >> 6] = m; sws[t >> 6] = ssum; }
  __syncthreads();
  if (t < 64) {
    float mm = (t < 16) ? swm[t] : -INFINITY;
    float ss = (t < 16) ? sws[t] : 0.f;
    for (int o = 8; o; o >>= 1) {
      float m2 = __shfl_down(mm, o, 64);
      float s2 = __shfl_down(ss, o, 64);
      if (m2 > mm) { ss = ss * expf(mm - m2) + s2; mm = m2; }
      else if (m2 != -INFINITY) ss += s2 * expf(m2 - mm);
    }
    if (t == 0) { swm[0] = mm; sws[0] = ss; }
  }
  __syncthreads();

  if (t == 0) {
    float M = swm[0], S = sws[0];
    int tc = tie_cnt;
    if (tc <= 128) {
      for (int a2 = 1; a2 < tc; ++a2) {
        int v = tie_j[a2]; int b2 = a2 - 1;
        while (b2 >= 0 && tie_j[b2] > v) { tie_j[b2 + 1] = tie_j[b2]; --b2; }
        tie_j[b2 + 1] = v;
      }
      for (uint32_t r = 0; r < need; ++r) {
        float v = mat_sim[mbase + tie_j[r]] / TEMP;
        if (v <= M) S += expf(v - M);
        else { S = S * expf(M - v) + 1.0f; M = v; }
      }
    } else {
      uint32_t taken = 0;
      for (int j = 0; j < NROWS && taken < need; ++j) {
        if (keys[j] == T) {
          float v = mat_sim[mbase + j] / TEMP;
          if (v <= M) S += expf(v - M);
          else { S = S * expf(M - v) + 1.0f; M = v; }
          ++taken;
        }
      }
    }
    float lp = l_pos / TEMP, pv = posv / TEMP, pw = posw / TEMP;
    float L = 0.f;
    { float X = fmaxf(M, lp); L += X + logf(expf(lp - X) + S * expf(M - X)) - lp; }
    { float X = fmaxf(M, pv); L += X + logf(expf(pv - X) + S * expf(M - X)) - pv; }
    { float X = fmaxf(M, pw); L += X + logf(expf(pw - X) + S * expf(M - X)) - pw; }
    row_loss[i] = L;
  }
}

// ---------------------------------------------------------------- finalize loss
__global__ void finalize_loss(const float* __restrict__ row_loss,
                              float* __restrict__ out) {
  __shared__ float sm[4];
  int t = threadIdx.x;
  float v = row_loss[t];
  for (int o = 32; o; o >>= 1) v += __shfl_down(v, o, 64);
  if ((t & 63) == 0) sm[t >> 6] = v;
  __syncthreads();
  if (t == 0) out[0] = (sm[0] + sm[1] + sm[2] + sm[3]) * (1.0f / BATCH);
}

// -------------------------------- fallback cleanup: copy front rows afterwards
__global__ void copy_front(const float* __restrict__ src,
                           float* __restrict__ dst, int n4) {
  int idx = blockIdx.x * blockDim.x + threadIdx.x;
  int stride = gridDim.x * blockDim.x;
  for (int i = idx; i < n4; i += stride) {
    float4 v = *(const float4*)&src[(size_t)i * 4];
    float* d = &dst[(size_t)i * 4];
    d[0] = v.x; d[1] = v.y; d[2] = v.z; d[3] = v.w;
  }
}

// --------------------------------------------- momentum update of touched rows
__global__ __launch_bounds__(256) void update_rows(
    const float* __restrict__ f, const float* __restrict__ features,
    const int* __restrict__ indexes, float* __restrict__ outF) {
  __shared__ float sred[16];
  const int i = blockIdx.x;
  const int row = indexes[i];
  for (int i2 = i + 1; i2 < BATCH; ++i2)
    if (indexes[i2] == row) return;          // last occurrence wins
  const int t = threadIdx.x;
  float ss = 0.f;
  for (int d = t; d < DIM; d += 256) {
    float u = 0.2f * features[(size_t)row * DIM + d] + 0.8f * f[(size_t)i * DIM + d];
    ss += u * u;
  }
  ss = block_sum(ss, sred);
  float nrm = fmaxf(sqrtf(ss), 1e-12f);
  for (int d = t; d < DIM; d += 256) {
    float u = 0.2f * features[(size_t)row * DIM + d] + 0.8f * f[(size_t)i * DIM + d];
    outF[(size_t)row * DIM + d] = u / nrm;
  }
}

// ------------------------------------------------------------------- launcher
extern "C" void kernel_launch(void* const* d_in, const int* in_sizes, int n_in,
                              void* d_out, int out_size, void* d_ws, size_t ws_size,
                              hipStream_t stream) {
  (void)in_sizes; (void)n_in; (void)out_size;
  const float* f        = (const float*)d_in[0];
  const float* f_nv     = (const float*)d_in[1];
  const float* features = (const float*)d_in[2];
  const int*   labels   = (const int*)d_in[3];
  const int*   indexes  = (const int*)d_in[4];
  float* out = (float*)d_out;

  // scratch: prefer d_ws; fall back to a region of d_out (then GEMM skips the
  // front rows of the fused copy and copy_front fixes them after finalize).
  const size_t need = ((size_t)BATCH * NROWS + 256) * sizeof(float);
  float* mat_sim;
  float* row_loss;
  int skip_rows;
  bool use_ws = (d_ws != nullptr) && (ws_size >= need);
  if (use_ws) {
    mat_sim = (float*)d_ws;
    row_loss = mat_sim + (size_t)BATCH * NROWS;
    skip_rows = 0;
  } else {
    mat_sim = out + 4;
    row_loss = out + 4 + (size_t)BATCH * NROWS;
    skip_rows = 4224;   // 33 * BN: scratch region rows, copied later
  }

  // kg1..kg3 = split(key(42), 3), partitionable threefry
  uint32_t c[6];
  { uint32_t a, b;
    tf2x32(0u, 42u, 0u, 0u, a, b); c[0] = a; c[1] = b;
    tf2x32(0u, 42u, 0u, 1u, a, b); c[2] = a; c[3] = b;
    tf2x32(0u, 42u, 0u, 2u, a, b); c[4] = a; c[5] = b; }

  gemm_fused<<<dim3(NROWS / BN), dim3(512), 0, stream>>>(
      f_nv, features, mat_sim, out + 1, skip_rows);
  sample_loss<<<dim3(BATCH), dim3(1024), 0, stream>>>(
      f, f_nv, features, labels, indexes, mat_sim, row_loss,
      c[0], c[1], c[2], c[3], c[4], c[5]);
  finalize_loss<<<dim3(1), dim3(256), 0, stream>>>(row_loss, out);
  if (!use_ws) {
    copy_front<<<dim3(2048), dim3(256), 0, stream>>>(
        features, out + 1, 4224 * DIM / 4);
  }
  update_rows<<<dim3(BATCH), dim3(256), 0, stream>>>(f, features, indexes, out + 1);
}